// Round 6
// baseline (188.708 us; speedup 1.0000x reference)
//
#include <hip/hip_runtime.h>

#define BINS 10
#define NTHR 256
#define MAXBLK 2048
#define UNROLL 5   // 10 iters/thread at this size -> exactly 2 batches, no tail

// ---------------------------------------------------------------------------
// loss = ( sum_e log2(arg_e) * (ln2/acc_sum[bin_e]) ) / n
//   arg_e = (gt==1) ? pre : (1-pre);  bin_e = min(floor(10*|pre-gt|), 9)
//   n = popcount(nonempty-bin mask); empty bins add 0 to the sum; tot cancels.
//
// R5 counters: partial kernel latency-bound (HBM 17%, VALU 12%, VGPR=12 ->
// only ONE float4-pair in flight). Fix: batch UNROLL independent pairs of
// global_load_dwordx4 before consuming (10 loads = 10KB/wave in flight).
// ---------------------------------------------------------------------------

__device__ __forceinline__ void ghm_elem(float pe, float te,
                                         const float* __restrict__ wtab,
                                         float& acc, unsigned int& mask) {
    float g = fabsf(pe - te);
    int bin = (int)(g * 10.0f);              // g>=0: trunc==floor
    bin = bin > (BINS - 1) ? (BINS - 1) : bin;
    mask |= (1u << bin);
    float arg = (te == 1.0f) ? pe : (1.0f - pe);
    acc = fmaf(__log2f(arg), wtab[bin], acc); // native v_log_f32; ln2 in wtab
}

__global__ __launch_bounds__(NTHR) void ghm_partial_kernel(
    const float* __restrict__ pre,
    const float* __restrict__ gt,
    const float* __restrict__ acc_sum,
    float* __restrict__ blk_sum,          // [gridDim.x] in d_ws
    unsigned int* __restrict__ blk_mask,  // [gridDim.x] in d_ws
    int n4,                               // float4 count
    int tot)                              // scalar count
{
    // ln2/acc_sum[b] in LDS: 10 consecutive dwords -> 10 distinct banks,
    // gather is broadcast/conflict-free (R5: SQ_LDS_BANK_CONFLICT == 0).
    __shared__ float wtab[BINS];
    if (threadIdx.x < BINS)
        wtab[threadIdx.x] = 0.69314718055994531f / acc_sum[threadIdx.x];
    __syncthreads();

    float acc0 = 0.0f, acc1 = 0.0f;       // 2 accs break the fmaf dep chain
    unsigned int mask = 0u;

    const float4* __restrict__ p4 = reinterpret_cast<const float4*>(pre);
    const float4* __restrict__ g4 = reinterpret_cast<const float4*>(gt);

    const int stride = gridDim.x * blockDim.x;
    int i = blockIdx.x * blockDim.x + threadIdx.x;

    // ---- batched main loop: UNROLL independent float4-pairs in flight ----
    for (; i + (UNROLL - 1) * stride < n4; i += UNROLL * stride) {
        float4 P[UNROLL], T[UNROLL];
#pragma unroll
        for (int u = 0; u < UNROLL; ++u) {   // static indices -> registers
            P[u] = p4[i + u * stride];
            T[u] = g4[i + u * stride];
        }
#pragma unroll
        for (int u = 0; u < UNROLL; ++u) {
            ghm_elem(P[u].x, T[u].x, wtab, acc0, mask);
            ghm_elem(P[u].y, T[u].y, wtab, acc1, mask);
            ghm_elem(P[u].z, T[u].z, wtab, acc0, mask);
            ghm_elem(P[u].w, T[u].w, wtab, acc1, mask);
        }
    }
    // ---- strided tail (unused at 2048*256 grid with n4 % stride == 0) ----
    for (; i < n4; i += stride) {
        float4 p = p4[i];
        float4 t = g4[i];
        ghm_elem(p.x, t.x, wtab, acc0, mask);
        ghm_elem(p.y, t.y, wtab, acc1, mask);
        ghm_elem(p.z, t.z, wtab, acc0, mask);
        ghm_elem(p.w, t.w, wtab, acc1, mask);
    }
    // ---- scalar tail (tot % 4) via first threads of block 0 ----
    const int rs = n4 * 4;
    const int rem = tot - rs;
    if (blockIdx.x == 0 && (int)threadIdx.x < rem) {
        ghm_elem(pre[rs + threadIdx.x], gt[rs + threadIdx.x], wtab, acc0, mask);
    }

    float acc = acc0 + acc1;

    // wave (64-lane) butterfly reduce
#pragma unroll
    for (int off = 32; off >= 1; off >>= 1) {
        acc  += __shfl_down(acc, off, 64);
        mask |= (unsigned int)__shfl_down((int)mask, off, 64);
    }

    // cross-wave via LDS (4 waves)
    __shared__ float ls[4];
    __shared__ unsigned int lm[4];
    const int lane = threadIdx.x & 63;
    const int wave = threadIdx.x >> 6;
    if (lane == 0) { ls[wave] = acc; lm[wave] = mask; }
    __syncthreads();
    if (threadIdx.x == 0) {
        blk_sum[blockIdx.x]  = ls[0] + ls[1] + ls[2] + ls[3];
        blk_mask[blockIdx.x] = lm[0] | lm[1] | lm[2] | lm[3];
    }
}

__global__ __launch_bounds__(NTHR) void ghm_finalize_kernel(
    const float* __restrict__ blk_sum,
    const unsigned int* __restrict__ blk_mask,
    float* __restrict__ out,
    int nblk)
{
    float acc = 0.0f;
    unsigned int mask = 0u;
    for (int i = threadIdx.x; i < nblk; i += NTHR) {
        acc  += blk_sum[i];
        mask |= blk_mask[i];
    }
#pragma unroll
    for (int off = 32; off >= 1; off >>= 1) {
        acc  += __shfl_down(acc, off, 64);
        mask |= (unsigned int)__shfl_down((int)mask, off, 64);
    }
    __shared__ float ls[4];
    __shared__ unsigned int lm[4];
    const int lane = threadIdx.x & 63;
    const int wave = threadIdx.x >> 6;
    if (lane == 0) { ls[wave] = acc; lm[wave] = mask; }
    __syncthreads();
    if (threadIdx.x == 0) {
        float total = ls[0] + ls[1] + ls[2] + ls[3];
        unsigned int m = lm[0] | lm[1] | lm[2] | lm[3];
        int n = __popc(m & ((1u << BINS) - 1u));
        out[0] = (n > 0) ? (total / (float)n) : total;
    }
}

extern "C" void kernel_launch(void* const* d_in, const int* in_sizes, int n_in,
                              void* d_out, int out_size, void* d_ws, size_t ws_size,
                              hipStream_t stream) {
    const float* pre     = (const float*)d_in[0];
    const float* gt      = (const float*)d_in[1];
    const float* acc_sum = (const float*)d_in[2];
    float* out = (float*)d_out;

    const int tot = in_sizes[0];   // 20,971,520
    const int n4  = tot / 4;

    int blocks = (n4 + NTHR - 1) / NTHR;
    if (blocks > MAXBLK) blocks = MAXBLK;
    if (blocks < 1) blocks = 1;

    float* blk_sum = (float*)d_ws;
    unsigned int* blk_mask = (unsigned int*)((char*)d_ws + MAXBLK * sizeof(float));

    ghm_partial_kernel<<<blocks, NTHR, 0, stream>>>(
        pre, gt, acc_sum, blk_sum, blk_mask, n4, tot);
    ghm_finalize_kernel<<<1, NTHR, 0, stream>>>(
        blk_sum, blk_mask, out, blocks);
}

// Round 7
// 171.614 us; speedup vs baseline: 1.0996x; 1.0996x over previous
//
#include <hip/hip_runtime.h>

#define BINS 10
#define NTHR 256
#define MAXBLK 2048

typedef float v4f __attribute__((ext_vector_type(4)));

// ---------------------------------------------------------------------------
// loss = ( sum_e log2(arg_e) * (ln2/acc_sum[bin_e]) ) / n
//   arg_e = (gt==1) ? pre : (1-pre);  bin_e = min(floor(10*|pre-gt|), 9)
//   n = popcount(nonempty-bin mask); empty bins add 0; tot cancels.
//
// R6 post-mortem: time invariant to data source (HBM vs L3) and to per-thread
// MLP -> suspected L3->CU fabric read-path ceiling (~2.7 TB/s). This round:
// benchmark-shaped streaming (contiguous per-block chunks + nontemporal
// loads + low-VGPR R5 body) as the final falsification of that ceiling.
// ---------------------------------------------------------------------------

__device__ __forceinline__ void ghm_elem(float pe, float te,
                                         const float* __restrict__ wtab,
                                         float& acc, unsigned int& mask) {
    float g = fabsf(pe - te);
    int bin = (int)(g * 10.0f);              // g>=0: trunc==floor
    bin = bin > (BINS - 1) ? (BINS - 1) : bin;
    mask |= (1u << bin);
    float arg = (te == 1.0f) ? pe : (1.0f - pe);
    acc = fmaf(__log2f(arg), wtab[bin], acc); // native v_log_f32; ln2 in wtab
}

__global__ __launch_bounds__(NTHR) void ghm_partial_kernel(
    const float* __restrict__ pre,
    const float* __restrict__ gt,
    const float* __restrict__ acc_sum,
    float* __restrict__ blk_sum,          // [gridDim.x] in d_ws
    unsigned int* __restrict__ blk_mask,  // [gridDim.x] in d_ws
    int n4,                               // float4 count
    int tot)                              // scalar count
{
    __shared__ float wtab[BINS];          // 10 dwords -> 10 banks, conflict-free
    if (threadIdx.x < BINS)
        wtab[threadIdx.x] = 0.69314718055994531f / acc_sum[threadIdx.x];
    __syncthreads();

    float acc0 = 0.0f, acc1 = 0.0f;       // 2 accs break the fmaf dep chain
    unsigned int mask = 0u;

    const v4f* __restrict__ p4 = reinterpret_cast<const v4f*>(pre);
    const v4f* __restrict__ g4 = reinterpret_cast<const v4f*>(gt);

    // Contiguous per-block chunk: block b owns [b*chunk, b*chunk+chunk).
    // At tot=20.97M: chunk=2560 f4 -> exactly 10 iters/thread, no remainder.
    const int chunk = (n4 + gridDim.x - 1) / gridDim.x;
    const int beg = blockIdx.x * chunk;
    int end = beg + chunk;
    if (end > n4) end = n4;

    for (int i = beg + (int)threadIdx.x; i < end; i += NTHR) {
        v4f p = __builtin_nontemporal_load(&p4[i]);  // use-once: no L2 alloc
        v4f t = __builtin_nontemporal_load(&g4[i]);
        ghm_elem(p.x, t.x, wtab, acc0, mask);
        ghm_elem(p.y, t.y, wtab, acc1, mask);
        ghm_elem(p.z, t.z, wtab, acc0, mask);
        ghm_elem(p.w, t.w, wtab, acc1, mask);
    }

    // scalar tail (tot % 4) via first threads of block 0
    const int rs = n4 * 4;
    const int rem = tot - rs;
    if (blockIdx.x == 0 && (int)threadIdx.x < rem) {
        ghm_elem(pre[rs + threadIdx.x], gt[rs + threadIdx.x], wtab, acc0, mask);
    }

    float acc = acc0 + acc1;

    // wave (64-lane) butterfly reduce
#pragma unroll
    for (int off = 32; off >= 1; off >>= 1) {
        acc  += __shfl_down(acc, off, 64);
        mask |= (unsigned int)__shfl_down((int)mask, off, 64);
    }

    // cross-wave via LDS (4 waves)
    __shared__ float ls[4];
    __shared__ unsigned int lm[4];
    const int lane = threadIdx.x & 63;
    const int wave = threadIdx.x >> 6;
    if (lane == 0) { ls[wave] = acc; lm[wave] = mask; }
    __syncthreads();
    if (threadIdx.x == 0) {
        blk_sum[blockIdx.x]  = ls[0] + ls[1] + ls[2] + ls[3];
        blk_mask[blockIdx.x] = lm[0] | lm[1] | lm[2] | lm[3];
    }
}

__global__ __launch_bounds__(NTHR) void ghm_finalize_kernel(
    const float* __restrict__ blk_sum,
    const unsigned int* __restrict__ blk_mask,
    float* __restrict__ out,
    int nblk)
{
    float acc = 0.0f;
    unsigned int mask = 0u;
    for (int i = threadIdx.x; i < nblk; i += NTHR) {
        acc  += blk_sum[i];
        mask |= blk_mask[i];
    }
#pragma unroll
    for (int off = 32; off >= 1; off >>= 1) {
        acc  += __shfl_down(acc, off, 64);
        mask |= (unsigned int)__shfl_down((int)mask, off, 64);
    }
    __shared__ float ls[4];
    __shared__ unsigned int lm[4];
    const int lane = threadIdx.x & 63;
    const int wave = threadIdx.x >> 6;
    if (lane == 0) { ls[wave] = acc; lm[wave] = mask; }
    __syncthreads();
    if (threadIdx.x == 0) {
        float total = ls[0] + ls[1] + ls[2] + ls[3];
        unsigned int m = lm[0] | lm[1] | lm[2] | lm[3];
        int n = __popc(m & ((1u << BINS) - 1u));
        out[0] = (n > 0) ? (total / (float)n) : total;
    }
}

extern "C" void kernel_launch(void* const* d_in, const int* in_sizes, int n_in,
                              void* d_out, int out_size, void* d_ws, size_t ws_size,
                              hipStream_t stream) {
    const float* pre     = (const float*)d_in[0];
    const float* gt      = (const float*)d_in[1];
    const float* acc_sum = (const float*)d_in[2];
    float* out = (float*)d_out;

    const int tot = in_sizes[0];   // 20,971,520
    const int n4  = tot / 4;

    int blocks = (n4 + NTHR - 1) / NTHR;
    if (blocks > MAXBLK) blocks = MAXBLK;
    if (blocks < 1) blocks = 1;

    float* blk_sum = (float*)d_ws;
    unsigned int* blk_mask = (unsigned int*)((char*)d_ws + MAXBLK * sizeof(float));

    ghm_partial_kernel<<<blocks, NTHR, 0, stream>>>(
        pre, gt, acc_sum, blk_sum, blk_mask, n4, tot);
    ghm_finalize_kernel<<<1, NTHR, 0, stream>>>(
        blk_sum, blk_mask, out, blocks);
}